// Round 9
// baseline (228.034 us; speedup 1.0000x reference)
//
#include <hip/hip_runtime.h>
#include <hip/hip_bf16.h>
#include <math.h>

// Problem: CausalSelfAttention  B=4 T=2048 D=1024 H=16 HD=64
// d_in: fp32 x[4,2048,1024], Wq,Wk,Wv,Wp[1024,1024], bp[1024]; d_out: fp32 y.
// Pipeline: cvt(fp32->bf16 into ws) -> qkv -> attn -> proj.
// V stored TRANSPOSED [B,H,HD,T]. attn v7: merged dual-q-tile sweep (q-tiles
// pr and 31-pr share one K/V staging sweep; each staged tile feeds both),
// m97-style LDS staging, XOR swizzle (both-sides), defer-max (THR=8, log2).

#define B_  4
#define T_  2048
#define D_  1024
#define H_  16
#define HD_ 64
#define M_  (B_ * T_)   // 8192 rows

typedef short bf16x8 __attribute__((ext_vector_type(8)));
typedef float f32x4  __attribute__((ext_vector_type(4)));

__device__ __forceinline__ f32x4 mfma16(bf16x8 a, bf16x8 b, f32x4 c) {
    return __builtin_amdgcn_mfma_f32_16x16x32_bf16(a, b, c, 0, 0, 0);
}

__device__ __forceinline__ void gl_lds16(const unsigned short* g, unsigned short* l) {
    __builtin_amdgcn_global_load_lds(
        (const __attribute__((address_space(1))) void*)g,
        (__attribute__((address_space(3))) void*)l, 16, 0, 0);
}

__device__ __forceinline__ unsigned short f2bf(float f) {
    union { __hip_bfloat16 h; unsigned short u; } cv;
    cv.h = __float2bfloat16(f);
    return cv.u;
}
__device__ __forceinline__ float bf2f(unsigned short u) {
    return __uint_as_float(((unsigned)u) << 16);
}
__device__ __forceinline__ float exp2_fast(float x) {
    return __builtin_amdgcn_exp2f(x);   // v_exp_f32: 2^x
}

struct su4 { unsigned short x, y, z, w; };

// ---------------------------------------------------------------------------
__global__ __launch_bounds__(256)
void cvt_kernel(const float* __restrict__ in, unsigned short* __restrict__ out) {
    const int i = blockIdx.x * 256 + threadIdx.x;
    const float4 v = ((const float4*)in)[i];
    su4 o;
    o.x = f2bf(v.x); o.y = f2bf(v.y); o.z = f2bf(v.z); o.w = f2bf(v.w);
    ((su4*)out)[i] = o;
}

__global__ __launch_bounds__(256)
void cvtw_kernel(const float* __restrict__ w0, const float* __restrict__ w1,
                 const float* __restrict__ w2, const float* __restrict__ w3,
                 unsigned short* __restrict__ o0, unsigned short* __restrict__ o1,
                 unsigned short* __restrict__ o2, unsigned short* __restrict__ o3) {
    const int y = blockIdx.y;
    const float* in       = (y == 0) ? w0 : (y == 1) ? w1 : (y == 2) ? w2 : w3;
    unsigned short* out   = (y == 0) ? o0 : (y == 1) ? o1 : (y == 2) ? o2 : o3;
    const int i = blockIdx.x * 256 + threadIdx.x;
    const float4 v = ((const float4*)in)[i];
    su4 o;
    o.x = f2bf(v.x); o.y = f2bf(v.y); o.z = f2bf(v.z); o.w = f2bf(v.w);
    ((su4*)out)[i] = o;
}

// ---------------------------------------------------------------------------
// Fused QKV GEMM: C = X @ W^T.  Q,K scattered to [B,H,T,HD]; V to [B,H,HD,T]
// via operand-swapped MFMA (acc holds C^T for the V section).
// ---------------------------------------------------------------------------
__global__ __launch_bounds__(256, 2)
void qkv_kernel(const unsigned short* __restrict__ X,
                const unsigned short* __restrict__ Wq,
                const unsigned short* __restrict__ Wk,
                const unsigned short* __restrict__ Wv,
                unsigned short* __restrict__ Qo,
                unsigned short* __restrict__ Ko,
                unsigned short* __restrict__ Vo)
{
    __shared__ unsigned short As[128 * 64];
    __shared__ unsigned short Bs[128 * 64];

    const int m0 = blockIdx.x * 128;
    const int by = blockIdx.y;
    const unsigned short* W = (by < 8) ? Wq : (by < 16) ? Wk : Wv;
    unsigned short*       O = (by < 8) ? Qo : (by < 16) ? Ko : Vo;
    const int n0   = (by & 7) * 128;
    const bool vsec = (by >= 16);
    const int tid  = threadIdx.x;
    const int lane = tid & 63;
    const int wv   = tid >> 6;
    const int wr   = (wv >> 1) * 64;
    const int wc   = (wv & 1) * 64;
    const int g    = lane >> 4;
    const int c    = lane & 15;

    f32x4 acc[4][4] = {};

    for (int k0 = 0; k0 < D_; k0 += 64) {
        #pragma unroll
        for (int i = 0; i < 4; ++i) {
            const int flat = i * 2048 + tid * 8;
            const int row = flat >> 6, col = flat & 63;
            gl_lds16(X + (size_t)(m0 + row) * D_ + k0 + col, As + flat);
            gl_lds16(W + (size_t)(n0 + row) * D_ + k0 + col, Bs + flat);
        }
        __syncthreads();
        #pragma unroll
        for (int kk = 0; kk < 64; kk += 32) {
            bf16x8 af[4], bg[4];
            #pragma unroll
            for (int mi = 0; mi < 4; ++mi)
                af[mi] = *(const bf16x8*)(As + (wr + mi * 16 + c) * 64 + kk + g * 8);
            #pragma unroll
            for (int ni = 0; ni < 4; ++ni)
                bg[ni] = *(const bf16x8*)(Bs + (wc + ni * 16 + c) * 64 + kk + g * 8);
            if (!vsec) {
                #pragma unroll
                for (int mi = 0; mi < 4; ++mi)
                    #pragma unroll
                    for (int ni = 0; ni < 4; ++ni)
                        acc[mi][ni] = mfma16(af[mi], bg[ni], acc[mi][ni]);
            } else {
                #pragma unroll
                for (int mi = 0; mi < 4; ++mi)
                    #pragma unroll
                    for (int ni = 0; ni < 4; ++ni)
                        acc[mi][ni] = mfma16(bg[ni], af[mi], acc[mi][ni]);
            }
        }
        __syncthreads();
    }

    if (!vsec) {
        #pragma unroll
        for (int mi = 0; mi < 4; ++mi)
            #pragma unroll
            for (int ni = 0; ni < 4; ++ni)
                #pragma unroll
                for (int r = 0; r < 4; ++r) {
                    const int m = m0 + wr + mi * 16 + g * 4 + r;
                    const int n = n0 + wc + ni * 16 + c;
                    const int b = m >> 11, t = m & (T_ - 1);
                    const int h = n >> 6,  hd = n & 63;
                    O[((size_t)((b << 4) + h) * T_ + t) * HD_ + hd] = f2bf(acc[mi][ni][r]);
                }
    } else {
        #pragma unroll
        for (int mi = 0; mi < 4; ++mi)
            #pragma unroll
            for (int ni = 0; ni < 4; ++ni)
                #pragma unroll
                for (int r = 0; r < 4; ++r) {
                    const int n = n0 + wc + ni * 16 + g * 4 + r;
                    const int m = m0 + wr + mi * 16 + c;
                    const int b = m >> 11, t = m & (T_ - 1);
                    const int h = n >> 6,  hd = n & 63;
                    O[((size_t)((b << 4) + h) * HD_ + hd) * T_ + t] = f2bf(acc[mi][ni][r]);
                }
    }
}

// ---------------------------------------------------------------------------
// P-transpose helper (verified lane math).
// ---------------------------------------------------------------------------
__device__ __forceinline__ bf16x8 ptrans(const f32x4& p0, const f32x4& p1,
                                         int lane, int g, int c) {
    unsigned int P32[2][2];
    P32[0][0] = (unsigned int)f2bf(p0[0]) | ((unsigned int)f2bf(p0[1]) << 16);
    P32[0][1] = (unsigned int)f2bf(p0[2]) | ((unsigned int)f2bf(p0[3]) << 16);
    P32[1][0] = (unsigned int)f2bf(p1[0]) | ((unsigned int)f2bf(p1[1]) << 16);
    P32[1][1] = (unsigned int)f2bf(p1[2]) | ((unsigned int)f2bf(p1[3]) << 16);
    const int sl0 = c + ((lane & 16) << 1);
    const int sl1 = sl0 + 16;
    const int q00 = __shfl((int)P32[0][0], sl0), q10 = __shfl((int)P32[1][0], sl0);
    const int q01 = __shfl((int)P32[0][1], sl0), q11 = __shfl((int)P32[1][1], sl0);
    const int q02 = __shfl((int)P32[0][0], sl1), q12 = __shfl((int)P32[1][0], sl1);
    const int q03 = __shfl((int)P32[0][1], sl1), q13 = __shfl((int)P32[1][1], sl1);
    const bool nhi = (g & 2) != 0;
    union { unsigned int u[4]; bf16x8 v; } pf;
    pf.u[0] = nhi ? q10 : q00;
    pf.u[1] = nhi ? q11 : q01;
    pf.u[2] = nhi ? q12 : q02;
    pf.u[3] = nhi ? q13 : q03;
    return pf.v;
}

// ---------------------------------------------------------------------------
// Causal flash attention v7: merged dual-q-tile sweep + LDS staging +
// defer-max.  Block handles q-tiles qtA=pr and qtB=31-pr in ONE sweep over
// K/V tiles 0..qtB; tile A is active while ti <= qtA.  Each staged tile and
// each LDS fragment load serves both q-tiles in the overlap region.
// ---------------------------------------------------------------------------
__global__ __launch_bounds__(256, 4)
void attn_kernel(const unsigned short* __restrict__ Q,
                 const unsigned short* __restrict__ K,
                 const unsigned short* __restrict__ VT,
                 unsigned short* __restrict__ Y)
{
    __shared__ unsigned short Ks[4096];   // K tile, swizzled
    __shared__ unsigned short Vs[4096];   // V^T tile, swizzled

    const int bh = blockIdx.x;          // fast axis -> XCD panel residency
    const int pr = blockIdx.y;          // 0..15
    const unsigned short* Qp  = Q  + (size_t)bh * T_ * HD_;
    const unsigned short* Kp  = K  + (size_t)bh * T_ * HD_;
    const unsigned short* VTp = VT + (size_t)bh * HD_ * T_;
    const int b = bh >> 4, h = bh & 15;

    const int tid  = threadIdx.x;
    const int lane = tid & 63;
    const int w    = tid >> 6;
    const int g    = lane >> 4;
    const int c    = lane & 15;
    const float SC = 0.18033688011112042f;   // (1/sqrt(64)) * log2(e)

    const int qtA = pr, qtB = 31 - pr;
    const int qwA = qtA * 64 + w * 16;
    const int qwB = qtB * 64 + w * 16;
    const int nt  = qtB + 1;

    // Staging constants (two 16B segments per 8KB half-tile)
    int srow[2], scol[2];
    #pragma unroll
    for (int i = 0; i < 2; ++i) {
        const int L = (i * 256 + tid) * 16;
        srow[i] = L >> 7;
        scol[i] = (L & 127) ^ ((srow[i] & 3) << 5);
    }

    // Q fragments for both q-tiles, pre-scaled (log2 domain)
    bf16x8 qfA[2], qfB[2];
    #pragma unroll
    for (int dk = 0; dk < 2; ++dk) {
        bf16x8 tA = *(const bf16x8*)(Qp + (size_t)(qwA + c) * HD_ + dk * 32 + g * 8);
        bf16x8 tB = *(const bf16x8*)(Qp + (size_t)(qwB + c) * HD_ + dk * 32 + g * 8);
        #pragma unroll
        for (int j = 0; j < 8; ++j) {
            tA[j] = (short)f2bf(bf2f((unsigned short)tA[j]) * SC);
            tB[j] = (short)f2bf(bf2f((unsigned short)tB[j]) * SC);
        }
        qfA[dk] = tA;
        qfB[dk] = tB;
    }

    float mA = -1e30f, lA = 0.f, mB = -1e30f, lB = 0.f;
    f32x4 oA[4] = {}, oB[4] = {};

    // Softmax (+defer-max) over one 64-key strip; returns al, skip.
    auto softmax64 = [&](f32x4 (&s0)[2], f32x4 (&s1)[2], int tb, int qw, bool last,
                         float& m_l, float& l_l, float& al_out, bool& skip_out) {
        if (last) {
            #pragma unroll
            for (int ni = 0; ni < 2; ++ni)
                #pragma unroll
                for (int r = 0; r < 4; ++r) {
                    const int kA = tb + ni * 16 + g * 4 + r;
                    s0[ni][r] = (kA      <= qw + c) ? s0[ni][r] : -1e30f;
                    s1[ni][r] = (kA + 32 <= qw + c) ? s1[ni][r] : -1e30f;
                }
        }
        float pmax = s0[0][0];
        #pragma unroll
        for (int ni = 0; ni < 2; ++ni)
            #pragma unroll
            for (int r = 0; r < 4; ++r) {
                pmax = fmaxf(pmax, s0[ni][r]);
                pmax = fmaxf(pmax, s1[ni][r]);
            }
        pmax = fmaxf(pmax, __shfl_xor(pmax, 16));
        pmax = fmaxf(pmax, __shfl_xor(pmax, 32));

        const bool skip = __all(pmax - m_l <= 8.0f);
        float al = 1.f;
        if (!skip) {
            const float mn = fmaxf(m_l, pmax);
            al = exp2_fast(m_l - mn);
            m_l = mn;
        }
        float rs = 0.f;
        #pragma unroll
        for (int ni = 0; ni < 2; ++ni)
            #pragma unroll
            for (int r = 0; r < 4; ++r) {
                const float e0 = exp2_fast(s0[ni][r] - m_l);
                const float e1 = exp2_fast(s1[ni][r] - m_l);
                s0[ni][r] = e0; s1[ni][r] = e1;
                rs += e0 + e1;
            }
        rs += __shfl_xor(rs, 16);
        rs += __shfl_xor(rs, 32);
        l_l = l_l * al + rs;
        al_out = al;
        skip_out = skip;
    };

    for (int ti = 0; ti < nt; ++ti) {
        const int tb = ti << 6;
        const bool actA = (ti <= qtA);

        // ---- stage K + V^T (linear dest, pre-swizzled src)
        #pragma unroll
        for (int i = 0; i < 2; ++i) {
            const int L = (i * 256 + tid) * 16;
            gl_lds16(Kp + (size_t)(tb + srow[i]) * HD_ + (scol[i] >> 1),
                     Ks + (L >> 1));
            gl_lds16(VTp + (size_t)srow[i] * T_ + tb + (scol[i] >> 1),
                     Vs + (L >> 1));
        }
        __syncthreads();

        // ---- K fragments (loaded once, feed both q-tiles)
        bf16x8 kf[8];
        #pragma unroll
        for (int s = 0; s < 2; ++s)
            #pragma unroll
            for (int ni = 0; ni < 2; ++ni)
                #pragma unroll
                for (int dk = 0; dk < 2; ++dk)
                    kf[s * 4 + ni * 2 + dk] = *(const bf16x8*)((const char*)Ks
                        + (s * 32 + ni * 16 + c) * 128
                        + ((dk * 64 + g * 16) ^ ((c & 3) << 5)));

        // ---- QK^T for B (always) and A (if active)
        f32x4 sB0[2] = {}, sB1[2] = {};
        f32x4 sA0[2] = {}, sA1[2] = {};
        #pragma unroll
        for (int ni = 0; ni < 2; ++ni)
            #pragma unroll
            for (int dk = 0; dk < 2; ++dk) {
                sB0[ni] = mfma16(kf[ni * 2 + dk],     qfB[dk], sB0[ni]);
                sB1[ni] = mfma16(kf[4 + ni * 2 + dk], qfB[dk], sB1[ni]);
            }
        if (actA) {
            #pragma unroll
            for (int ni = 0; ni < 2; ++ni)
                #pragma unroll
                for (int dk = 0; dk < 2; ++dk) {
                    sA0[ni] = mfma16(kf[ni * 2 + dk],     qfA[dk], sA0[ni]);
                    sA1[ni] = mfma16(kf[4 + ni * 2 + dk], qfA[dk], sA1[ni]);
                }
        }

        // ---- softmax + ptrans
        float alB, alA = 1.f;
        bool skB, skA = true;
        softmax64(sB0, sB1, tb, qwB, ti == qtB, mB, lB, alB, skB);
        const bf16x8 pfB0 = ptrans(sB0[0], sB0[1], lane, g, c);
        const bf16x8 pfB1 = ptrans(sB1[0], sB1[1], lane, g, c);
        bf16x8 pfA0, pfA1;
        if (actA) {
            softmax64(sA0, sA1, tb, qwA, ti == qtA, mA, lA, alA, skA);
            pfA0 = ptrans(sA0[0], sA0[1], lane, g, c);
            pfA1 = ptrans(sA1[0], sA1[1], lane, g, c);
        }

        // ---- V fragments (loaded once, feed both q-tiles) + PV
        #pragma unroll
        for (int dn = 0; dn < 4; ++dn) {
            const int row = dn * 16 + c;
            const bf16x8 vA = *(const bf16x8*)((const char*)Vs
                + row * 128 + ((g * 16)      ^ ((c & 3) << 5)));
            const bf16x8 vB = *(const bf16x8*)((const char*)Vs
                + row * 128 + ((64 + g * 16) ^ ((c & 3) << 5)));
            if (!skB) {
                #pragma unroll
                for (int r = 0; r < 4; ++r)
                    oB[dn][r] *= alB;
            }
            oB[dn] = mfma16(vA, pfB0, oB[dn]);
            oB[dn] = mfma16(vB, pfB1, oB[dn]);
            if (actA) {
                if (!skA) {
                    #pragma unroll
                    for (int r = 0; r < 4; ++r)
                        oA[dn][r] *= alA;
                }
                oA[dn] = mfma16(vA, pfA0, oA[dn]);
                oA[dn] = mfma16(vB, pfA1, oA[dn]);
            }
        }
        __syncthreads();
    }

    // ---- epilogues
    {
        const float li = 1.f / lA;
        const size_t rowoff = (size_t)(b * T_ + qwA + c) * D_ + h * 64;
        #pragma unroll
        for (int dn = 0; dn < 4; ++dn) {
            const unsigned int u0 = (unsigned int)f2bf(oA[dn][0] * li)
                                  | ((unsigned int)f2bf(oA[dn][1] * li) << 16);
            const unsigned int u1 = (unsigned int)f2bf(oA[dn][2] * li)
                                  | ((unsigned int)f2bf(oA[dn][3] * li) << 16);
            uint2 st; st.x = u0; st.y = u1;
            *(uint2*)(Y + rowoff + dn * 16 + g * 4) = st;
        }
    }
    {
        const float li = 1.f / lB;
        const size_t rowoff = (size_t)(b * T_ + qwB + c) * D_ + h * 64;
        #pragma unroll
        for (int dn = 0; dn < 4; ++dn) {
            const unsigned int u0 = (unsigned int)f2bf(oB[dn][0] * li)
                                  | ((unsigned int)f2bf(oB[dn][1] * li) << 16);
            const unsigned int u1 = (unsigned int)f2bf(oB[dn][2] * li)
                                  | ((unsigned int)f2bf(oB[dn][3] * li) << 16);
            uint2 st; st.x = u0; st.y = u1;
            *(uint2*)(Y + rowoff + dn * 16 + g * 4) = st;
        }
    }
}

// ---------------------------------------------------------------------------
// Output projection:  out = Y @ Wp^T + bp.  Y bf16[8192,1024]; out fp32.
// ---------------------------------------------------------------------------
__global__ __launch_bounds__(256, 2)
void proj_kernel(const unsigned short* __restrict__ Yin,
                 const unsigned short* __restrict__ Wp,
                 const float* __restrict__ bp,
                 float* __restrict__ Out)
{
    __shared__ unsigned short As[128 * 64];
    __shared__ unsigned short Bs[128 * 64];

    const int m0 = blockIdx.x * 128;
    const int n0 = blockIdx.y * 128;
    const int tid  = threadIdx.x;
    const int lane = tid & 63;
    const int wv   = tid >> 6;
    const int wr   = (wv >> 1) * 64;
    const int wc   = (wv & 1) * 64;
    const int g    = lane >> 4;
    const int c    = lane & 15;

    f32x4 acc[4][4] = {};

    for (int k0 = 0; k0 < D_; k0 += 64) {
        #pragma unroll
        for (int i = 0; i < 4; ++i) {
            const int flat = i * 2048 + tid * 8;
            const int row = flat >> 6, col = flat & 63;
            gl_lds16(Yin + (size_t)(m0 + row) * D_ + k0 + col, As + flat);
            gl_lds16(Wp  + (size_t)(n0 + row) * D_ + k0 + col, Bs + flat);
        }
        __syncthreads();
        #pragma unroll
        for (int kk = 0; kk < 64; kk += 32) {
            bf16x8 af[4], bg[4];
            #pragma unroll
            for (int mi = 0; mi < 4; ++mi)
                af[mi] = *(const bf16x8*)(As + (wr + mi * 16 + c) * 64 + kk + g * 8);
            #pragma unroll
            for (int ni = 0; ni < 4; ++ni)
                bg[ni] = *(const bf16x8*)(Bs + (wc + ni * 16 + c) * 64 + kk + g * 8);
            #pragma unroll
            for (int mi = 0; mi < 4; ++mi)
                #pragma unroll
                for (int ni = 0; ni < 4; ++ni)
                    acc[mi][ni] = mfma16(af[mi], bg[ni], acc[mi][ni]);
        }
        __syncthreads();
    }

    #pragma unroll
    for (int mi = 0; mi < 4; ++mi) {
        #pragma unroll
        for (int ni = 0; ni < 4; ++ni) {
            const int n = n0 + wc + ni * 16 + c;
            const float bb = bp[n];
            #pragma unroll
            for (int r = 0; r < 4; ++r) {
                const int m = m0 + wr + mi * 16 + g * 4 + r;
                Out[(size_t)m * D_ + n] = acc[mi][ni][r] + bb;
            }
        }
    }
}

// ---------------------------------------------------------------------------
extern "C" void kernel_launch(void* const* d_in, const int* in_sizes, int n_in,
                              void* d_out, int out_size, void* d_ws, size_t ws_size,
                              hipStream_t stream) {
    const float* x  = (const float*)d_in[0];
    const float* Wq = (const float*)d_in[1];
    const float* Wk = (const float*)d_in[2];
    const float* Wv = (const float*)d_in[3];
    const float* Wp = (const float*)d_in[4];
    const float* bp = (const float*)d_in[5];
    float* out = (float*)d_out;

    const size_t SZ  = (size_t)M_ * D_;      // 8388608
    const size_t WSZ = (size_t)D_ * D_;      // 1048576
    unsigned short* ws = (unsigned short*)d_ws;
    unsigned short* XB  = ws;                 // also Y after qkv
    unsigned short* WQB = XB  + SZ;
    unsigned short* WKB = WQB + WSZ;
    unsigned short* WVB = WKB + WSZ;
    unsigned short* WPB = WVB + WSZ;
    unsigned short* Qw  = WPB + WSZ;
    unsigned short* Kw  = Qw + SZ;
    unsigned short* Vw  = Kw + SZ;            // V^T [B,H,HD,T]
    unsigned short* Yw  = XB;                 // overlay: x_bf16 dead after qkv

    dim3 blk(256);
    cvt_kernel <<<dim3(SZ / 1024),     blk, 0, stream>>>(x, XB);
    cvtw_kernel<<<dim3(WSZ / 1024, 4), blk, 0, stream>>>(Wq, Wk, Wv, Wp, WQB, WKB, WVB, WPB);

    qkv_kernel <<<dim3(M_ / 128, 24), blk, 0, stream>>>(XB, WQB, WKB, WVB, Qw, Kw, Vw);
    attn_kernel<<<dim3(B_ * H_, 16), blk, 0, stream>>>(Qw, Kw, Vw, Yw);
    proj_kernel<<<dim3(M_ / 128, D_ / 128), blk, 0, stream>>>(Yw, WPB, bp, out);
}

// Round 10
// 205.356 us; speedup vs baseline: 1.1104x; 1.1104x over previous
//
#include <hip/hip_runtime.h>
#include <hip/hip_bf16.h>
#include <math.h>

// Problem: CausalSelfAttention  B=4 T=2048 D=1024 H=16 HD=64
// d_in: fp32 x[4,2048,1024], Wq,Wk,Wv,Wp[1024,1024], bp[1024]; d_out: fp32 y.
// Pipeline: cvt(fp32->bf16 into ws) -> qkv -> attn -> proj.
// V stored TRANSPOSED [B,H,HD,T]. attn v8 = round-8 body (LDS-staged K/V,
// XOR swizzle both-sides, swapped QK/PV, ptrans) + one q-tile per block
// (grid 64x32, qt=31-by LPT, 8 blocks/CU) + defer-max (THR=8, log2 domain).

#define B_  4
#define T_  2048
#define D_  1024
#define H_  16
#define HD_ 64
#define M_  (B_ * T_)   // 8192 rows

typedef short bf16x8 __attribute__((ext_vector_type(8)));
typedef float f32x4  __attribute__((ext_vector_type(4)));

__device__ __forceinline__ f32x4 mfma16(bf16x8 a, bf16x8 b, f32x4 c) {
    return __builtin_amdgcn_mfma_f32_16x16x32_bf16(a, b, c, 0, 0, 0);
}

__device__ __forceinline__ void gl_lds16(const unsigned short* g, unsigned short* l) {
    __builtin_amdgcn_global_load_lds(
        (const __attribute__((address_space(1))) void*)g,
        (__attribute__((address_space(3))) void*)l, 16, 0, 0);
}

__device__ __forceinline__ unsigned short f2bf(float f) {
    union { __hip_bfloat16 h; unsigned short u; } cv;
    cv.h = __float2bfloat16(f);
    return cv.u;
}
__device__ __forceinline__ float bf2f(unsigned short u) {
    return __uint_as_float(((unsigned)u) << 16);
}
__device__ __forceinline__ float exp2_fast(float x) {
    return __builtin_amdgcn_exp2f(x);   // v_exp_f32: 2^x
}

struct su4 { unsigned short x, y, z, w; };

// ---------------------------------------------------------------------------
__global__ __launch_bounds__(256)
void cvt_kernel(const float* __restrict__ in, unsigned short* __restrict__ out) {
    const int i = blockIdx.x * 256 + threadIdx.x;
    const float4 v = ((const float4*)in)[i];
    su4 o;
    o.x = f2bf(v.x); o.y = f2bf(v.y); o.z = f2bf(v.z); o.w = f2bf(v.w);
    ((su4*)out)[i] = o;
}

__global__ __launch_bounds__(256)
void cvtw_kernel(const float* __restrict__ w0, const float* __restrict__ w1,
                 const float* __restrict__ w2, const float* __restrict__ w3,
                 unsigned short* __restrict__ o0, unsigned short* __restrict__ o1,
                 unsigned short* __restrict__ o2, unsigned short* __restrict__ o3) {
    const int y = blockIdx.y;
    const float* in       = (y == 0) ? w0 : (y == 1) ? w1 : (y == 2) ? w2 : w3;
    unsigned short* out   = (y == 0) ? o0 : (y == 1) ? o1 : (y == 2) ? o2 : o3;
    const int i = blockIdx.x * 256 + threadIdx.x;
    const float4 v = ((const float4*)in)[i];
    su4 o;
    o.x = f2bf(v.x); o.y = f2bf(v.y); o.z = f2bf(v.z); o.w = f2bf(v.w);
    ((su4*)out)[i] = o;
}

// ---------------------------------------------------------------------------
// Fused QKV GEMM: C = X @ W^T.  Q,K scattered to [B,H,T,HD]; V to [B,H,HD,T]
// via operand-swapped MFMA (acc holds C^T for the V section).
// ---------------------------------------------------------------------------
__global__ __launch_bounds__(256, 2)
void qkv_kernel(const unsigned short* __restrict__ X,
                const unsigned short* __restrict__ Wq,
                const unsigned short* __restrict__ Wk,
                const unsigned short* __restrict__ Wv,
                unsigned short* __restrict__ Qo,
                unsigned short* __restrict__ Ko,
                unsigned short* __restrict__ Vo)
{
    __shared__ unsigned short As[128 * 64];
    __shared__ unsigned short Bs[128 * 64];

    const int m0 = blockIdx.x * 128;
    const int by = blockIdx.y;
    const unsigned short* W = (by < 8) ? Wq : (by < 16) ? Wk : Wv;
    unsigned short*       O = (by < 8) ? Qo : (by < 16) ? Ko : Vo;
    const int n0   = (by & 7) * 128;
    const bool vsec = (by >= 16);
    const int tid  = threadIdx.x;
    const int lane = tid & 63;
    const int wv   = tid >> 6;
    const int wr   = (wv >> 1) * 64;
    const int wc   = (wv & 1) * 64;
    const int g    = lane >> 4;
    const int c    = lane & 15;

    f32x4 acc[4][4] = {};

    for (int k0 = 0; k0 < D_; k0 += 64) {
        #pragma unroll
        for (int i = 0; i < 4; ++i) {
            const int flat = i * 2048 + tid * 8;
            const int row = flat >> 6, col = flat & 63;
            gl_lds16(X + (size_t)(m0 + row) * D_ + k0 + col, As + flat);
            gl_lds16(W + (size_t)(n0 + row) * D_ + k0 + col, Bs + flat);
        }
        __syncthreads();
        #pragma unroll
        for (int kk = 0; kk < 64; kk += 32) {
            bf16x8 af[4], bg[4];
            #pragma unroll
            for (int mi = 0; mi < 4; ++mi)
                af[mi] = *(const bf16x8*)(As + (wr + mi * 16 + c) * 64 + kk + g * 8);
            #pragma unroll
            for (int ni = 0; ni < 4; ++ni)
                bg[ni] = *(const bf16x8*)(Bs + (wc + ni * 16 + c) * 64 + kk + g * 8);
            if (!vsec) {
                #pragma unroll
                for (int mi = 0; mi < 4; ++mi)
                    #pragma unroll
                    for (int ni = 0; ni < 4; ++ni)
                        acc[mi][ni] = mfma16(af[mi], bg[ni], acc[mi][ni]);
            } else {
                #pragma unroll
                for (int mi = 0; mi < 4; ++mi)
                    #pragma unroll
                    for (int ni = 0; ni < 4; ++ni)
                        acc[mi][ni] = mfma16(bg[ni], af[mi], acc[mi][ni]);
            }
        }
        __syncthreads();
    }

    if (!vsec) {
        #pragma unroll
        for (int mi = 0; mi < 4; ++mi)
            #pragma unroll
            for (int ni = 0; ni < 4; ++ni)
                #pragma unroll
                for (int r = 0; r < 4; ++r) {
                    const int m = m0 + wr + mi * 16 + g * 4 + r;
                    const int n = n0 + wc + ni * 16 + c;
                    const int b = m >> 11, t = m & (T_ - 1);
                    const int h = n >> 6,  hd = n & 63;
                    O[((size_t)((b << 4) + h) * T_ + t) * HD_ + hd] = f2bf(acc[mi][ni][r]);
                }
    } else {
        #pragma unroll
        for (int mi = 0; mi < 4; ++mi)
            #pragma unroll
            for (int ni = 0; ni < 4; ++ni)
                #pragma unroll
                for (int r = 0; r < 4; ++r) {
                    const int n = n0 + wc + ni * 16 + g * 4 + r;
                    const int m = m0 + wr + mi * 16 + c;
                    const int b = m >> 11, t = m & (T_ - 1);
                    const int h = n >> 6,  hd = n & 63;
                    O[((size_t)((b << 4) + h) * HD_ + hd) * T_ + t] = f2bf(acc[mi][ni][r]);
                }
    }
}

// ---------------------------------------------------------------------------
// P-transpose helper (verified lane math).
// ---------------------------------------------------------------------------
__device__ __forceinline__ bf16x8 ptrans(const f32x4& p0, const f32x4& p1,
                                         int lane, int g, int c) {
    unsigned int P32[2][2];
    P32[0][0] = (unsigned int)f2bf(p0[0]) | ((unsigned int)f2bf(p0[1]) << 16);
    P32[0][1] = (unsigned int)f2bf(p0[2]) | ((unsigned int)f2bf(p0[3]) << 16);
    P32[1][0] = (unsigned int)f2bf(p1[0]) | ((unsigned int)f2bf(p1[1]) << 16);
    P32[1][1] = (unsigned int)f2bf(p1[2]) | ((unsigned int)f2bf(p1[3]) << 16);
    const int sl0 = c + ((lane & 16) << 1);
    const int sl1 = sl0 + 16;
    const int q00 = __shfl((int)P32[0][0], sl0), q10 = __shfl((int)P32[1][0], sl0);
    const int q01 = __shfl((int)P32[0][1], sl0), q11 = __shfl((int)P32[1][1], sl0);
    const int q02 = __shfl((int)P32[0][0], sl1), q12 = __shfl((int)P32[1][0], sl1);
    const int q03 = __shfl((int)P32[0][1], sl1), q13 = __shfl((int)P32[1][1], sl1);
    const bool nhi = (g & 2) != 0;
    union { unsigned int u[4]; bf16x8 v; } pf;
    pf.u[0] = nhi ? q10 : q00;
    pf.u[1] = nhi ? q11 : q01;
    pf.u[2] = nhi ? q12 : q02;
    pf.u[3] = nhi ? q13 : q03;
    return pf.v;
}

// ---------------------------------------------------------------------------
// Causal flash attention v8: round-8 body, one q-tile per block (2048 blocks,
// 8/CU), LPT ordering, defer-max.
// LDS: K tile [64][64] bf16 (8KB) + V^T tile [64][64] (8KB) = 16KB.
// Swizzle: phys_byte = row*128 + (log_byte ^ ((row&3)<<5)); staged via
// linear gl_lds dest + pre-swizzled global source (involution).
// ---------------------------------------------------------------------------
__global__ __launch_bounds__(256, 4)
void attn_kernel(const unsigned short* __restrict__ Q,
                 const unsigned short* __restrict__ K,
                 const unsigned short* __restrict__ VT,
                 unsigned short* __restrict__ Y)
{
    __shared__ unsigned short Ks[4096];   // K tile, swizzled
    __shared__ unsigned short Vs[4096];   // V^T tile, swizzled

    const int bh = blockIdx.x;          // fast axis -> XCD panel residency
    const int qt = 31 - blockIdx.y;     // LPT: heaviest q-tiles first
    const unsigned short* Qp  = Q  + (size_t)bh * T_ * HD_;
    const unsigned short* Kp  = K  + (size_t)bh * T_ * HD_;
    const unsigned short* VTp = VT + (size_t)bh * HD_ * T_;
    const int b = bh >> 4, h = bh & 15;

    const int tid  = threadIdx.x;
    const int lane = tid & 63;
    const int w    = tid >> 6;
    const int g    = lane >> 4;
    const int c    = lane & 15;
    const float SC = 0.18033688011112042f;   // (1/sqrt(64)) * log2(e)

    const int qw = qt * 64 + w * 16;
    const int nt = qt + 1;              // 64-key tiles; last is diagonal

    // Staging constants for this thread (two 16B segments per 8KB half-tile)
    int srow[2], scol[2];
    #pragma unroll
    for (int i = 0; i < 2; ++i) {
        const int L = (i * 256 + tid) * 16;
        srow[i] = L >> 7;                                   // 0..63
        scol[i] = (L & 127) ^ ((srow[i] & 3) << 5);         // pre-swizzled src col (bytes)
    }

    // Q as B-operand frags, pre-scaled (log2 domain)
    bf16x8 qf[2];
    #pragma unroll
    for (int dk = 0; dk < 2; ++dk) {
        bf16x8 t = *(const bf16x8*)(Qp + (size_t)(qw + c) * HD_ + dk * 32 + g * 8);
        #pragma unroll
        for (int j = 0; j < 8; ++j)
            t[j] = (short)f2bf(bf2f((unsigned short)t[j]) * SC);
        qf[dk] = t;
    }

    float m_l = -1e30f, l_l = 0.f;
    f32x4 oacc[4] = {};

    for (int ti = 0; ti < nt; ++ti) {
        const int tb = ti << 6;
        const bool last = (ti == nt - 1);

        // ---- stage K (8KB) + V^T (8KB), linear dest, pre-swizzled src
        #pragma unroll
        for (int i = 0; i < 2; ++i) {
            const int L = (i * 256 + tid) * 16;
            gl_lds16(Kp + (size_t)(tb + srow[i]) * HD_ + (scol[i] >> 1),
                     Ks + (L >> 1));
            gl_lds16(VTp + (size_t)srow[i] * T_ + tb + (scol[i] >> 1),
                     Vs + (L >> 1));
        }
        __syncthreads();

        // ---- QK^T (swapped): sA (keys tb..tb+31), sB (tb+32..tb+63)
        f32x4 sA[2] = {}, sB[2] = {};
        #pragma unroll
        for (int ni = 0; ni < 2; ++ni)
            #pragma unroll
            for (int dk = 0; dk < 2; ++dk) {
                const int rA = ni * 16 + c;
                const int rB = 32 + ni * 16 + c;
                const bf16x8 kA = *(const bf16x8*)((const char*)Ks
                    + rA * 128 + ((dk * 64 + g * 16) ^ ((c & 3) << 5)));
                const bf16x8 kB = *(const bf16x8*)((const char*)Ks
                    + rB * 128 + ((dk * 64 + g * 16) ^ ((c & 3) << 5)));
                sA[ni] = mfma16(kA, qf[dk], sA[ni]);
                sB[ni] = mfma16(kB, qf[dk], sB[ni]);
            }

        // ---- mask (diagonal tile only)
        if (last) {
            #pragma unroll
            for (int ni = 0; ni < 2; ++ni)
                #pragma unroll
                for (int r = 0; r < 4; ++r) {
                    const int kA = tb + ni * 16 + g * 4 + r;
                    sA[ni][r] = (kA      <= qw + c) ? sA[ni][r] : -1e30f;
                    sB[ni][r] = (kA + 32 <= qw + c) ? sB[ni][r] : -1e30f;
                }
        }

        // ---- online softmax (per-lane over 16 vals + 2 shuffles) + defer-max
        float pmax = sA[0][0];
        #pragma unroll
        for (int ni = 0; ni < 2; ++ni)
            #pragma unroll
            for (int r = 0; r < 4; ++r) {
                pmax = fmaxf(pmax, sA[ni][r]);
                pmax = fmaxf(pmax, sB[ni][r]);
            }
        pmax = fmaxf(pmax, __shfl_xor(pmax, 16));
        pmax = fmaxf(pmax, __shfl_xor(pmax, 32));

        const bool skip = __all(pmax - m_l <= 8.0f);
        float al = 1.f;
        if (!skip) {
            const float mn = fmaxf(m_l, pmax);
            al = exp2_fast(m_l - mn);
            m_l = mn;
        }

        float rs = 0.f;
        #pragma unroll
        for (int ni = 0; ni < 2; ++ni)
            #pragma unroll
            for (int r = 0; r < 4; ++r) {
                const float eA = exp2_fast(sA[ni][r] - m_l);
                const float eB = exp2_fast(sB[ni][r] - m_l);
                sA[ni][r] = eA; sB[ni][r] = eB;
                rs += eA + eB;
            }
        rs += __shfl_xor(rs, 16);
        rs += __shfl_xor(rs, 32);
        l_l = l_l * al + rs;

        // ---- P transpose to PV A-fragments
        const bf16x8 pfA = ptrans(sA[0], sA[1], lane, g, c);
        const bf16x8 pfB = ptrans(sB[0], sB[1], lane, g, c);

        // ---- rescale (skipped when deferred) + PV (swapped)
        #pragma unroll
        for (int dn = 0; dn < 4; ++dn) {
            const int row = dn * 16 + c;
            const bf16x8 vA = *(const bf16x8*)((const char*)Vs
                + row * 128 + ((g * 16)      ^ ((c & 3) << 5)));
            const bf16x8 vB = *(const bf16x8*)((const char*)Vs
                + row * 128 + ((64 + g * 16) ^ ((c & 3) << 5)));
            if (!skip) {
                #pragma unroll
                for (int r = 0; r < 4; ++r)
                    oacc[dn][r] *= al;
            }
            oacc[dn] = mfma16(vA, pfA, oacc[dn]);
            oacc[dn] = mfma16(vB, pfB, oacc[dn]);
        }
        __syncthreads();
    }

    // ---- epilogue: O[q = qw+c][d = dn*16 + g*4 + r]
    const float li = 1.f / l_l;
    const size_t rowoff = (size_t)(b * T_ + qw + c) * D_ + h * 64;
    #pragma unroll
    for (int dn = 0; dn < 4; ++dn) {
        const unsigned int u0 = (unsigned int)f2bf(oacc[dn][0] * li)
                              | ((unsigned int)f2bf(oacc[dn][1] * li) << 16);
        const unsigned int u1 = (unsigned int)f2bf(oacc[dn][2] * li)
                              | ((unsigned int)f2bf(oacc[dn][3] * li) << 16);
        uint2 st; st.x = u0; st.y = u1;
        *(uint2*)(Y + rowoff + dn * 16 + g * 4) = st;
    }
}

// ---------------------------------------------------------------------------
// Output projection:  out = Y @ Wp^T + bp.  Y bf16[8192,1024]; out fp32.
// ---------------------------------------------------------------------------
__global__ __launch_bounds__(256, 2)
void proj_kernel(const unsigned short* __restrict__ Yin,
                 const unsigned short* __restrict__ Wp,
                 const float* __restrict__ bp,
                 float* __restrict__ Out)
{
    __shared__ unsigned short As[128 * 64];
    __shared__ unsigned short Bs[128 * 64];

    const int m0 = blockIdx.x * 128;
    const int n0 = blockIdx.y * 128;
    const int tid  = threadIdx.x;
    const int lane = tid & 63;
    const int wv   = tid >> 6;
    const int wr   = (wv >> 1) * 64;
    const int wc   = (wv & 1) * 64;
    const int g    = lane >> 4;
    const int c    = lane & 15;

    f32x4 acc[4][4] = {};

    for (int k0 = 0; k0 < D_; k0 += 64) {
        #pragma unroll
        for (int i = 0; i < 4; ++i) {
            const int flat = i * 2048 + tid * 8;
            const int row = flat >> 6, col = flat & 63;
            gl_lds16(Yin + (size_t)(m0 + row) * D_ + k0 + col, As + flat);
            gl_lds16(Wp  + (size_t)(n0 + row) * D_ + k0 + col, Bs + flat);
        }
        __syncthreads();
        #pragma unroll
        for (int kk = 0; kk < 64; kk += 32) {
            bf16x8 af[4], bg[4];
            #pragma unroll
            for (int mi = 0; mi < 4; ++mi)
                af[mi] = *(const bf16x8*)(As + (wr + mi * 16 + c) * 64 + kk + g * 8);
            #pragma unroll
            for (int ni = 0; ni < 4; ++ni)
                bg[ni] = *(const bf16x8*)(Bs + (wc + ni * 16 + c) * 64 + kk + g * 8);
            #pragma unroll
            for (int mi = 0; mi < 4; ++mi)
                #pragma unroll
                for (int ni = 0; ni < 4; ++ni)
                    acc[mi][ni] = mfma16(af[mi], bg[ni], acc[mi][ni]);
        }
        __syncthreads();
    }

    #pragma unroll
    for (int mi = 0; mi < 4; ++mi) {
        #pragma unroll
        for (int ni = 0; ni < 4; ++ni) {
            const int n = n0 + wc + ni * 16 + c;
            const float bb = bp[n];
            #pragma unroll
            for (int r = 0; r < 4; ++r) {
                const int m = m0 + wr + mi * 16 + g * 4 + r;
                Out[(size_t)m * D_ + n] = acc[mi][ni][r] + bb;
            }
        }
    }
}

// ---------------------------------------------------------------------------
extern "C" void kernel_launch(void* const* d_in, const int* in_sizes, int n_in,
                              void* d_out, int out_size, void* d_ws, size_t ws_size,
                              hipStream_t stream) {
    const float* x  = (const float*)d_in[0];
    const float* Wq = (const float*)d_in[1];
    const float* Wk = (const float*)d_in[2];
    const float* Wv = (const float*)d_in[3];
    const float* Wp = (const float*)d_in[4];
    const float* bp = (const float*)d_in[5];
    float* out = (float*)d_out;

    const size_t SZ  = (size_t)M_ * D_;      // 8388608
    const size_t WSZ = (size_t)D_ * D_;      // 1048576
    unsigned short* ws = (unsigned short*)d_ws;
    unsigned short* XB  = ws;                 // also Y after qkv
    unsigned short* WQB = XB  + SZ;
    unsigned short* WKB = WQB + WSZ;
    unsigned short* WVB = WKB + WSZ;
    unsigned short* WPB = WVB + WSZ;
    unsigned short* Qw  = WPB + WSZ;
    unsigned short* Kw  = Qw + SZ;
    unsigned short* Vw  = Kw + SZ;            // V^T [B,H,HD,T]
    unsigned short* Yw  = XB;                 // overlay: x_bf16 dead after qkv

    dim3 blk(256);
    cvt_kernel <<<dim3(SZ / 1024),     blk, 0, stream>>>(x, XB);
    cvtw_kernel<<<dim3(WSZ / 1024, 4), blk, 0, stream>>>(Wq, Wk, Wv, Wp, WQB, WKB, WVB, WPB);

    qkv_kernel <<<dim3(M_ / 128, 24), blk, 0, stream>>>(XB, WQB, WKB, WVB, Qw, Kw, Vw);
    attn_kernel<<<dim3(B_ * H_, T_ / 64), blk, 0, stream>>>(Qw, Kw, Vw, Yw);
    proj_kernel<<<dim3(M_ / 128, D_ / 128), blk, 0, stream>>>(Yw, WPB, bp, out);
}

// Round 11
// 202.680 us; speedup vs baseline: 1.1251x; 1.0132x over previous
//
#include <hip/hip_runtime.h>
#include <hip/hip_bf16.h>
#include <math.h>

// Problem: CausalSelfAttention  B=4 T=2048 D=1024 H=16 HD=64
// d_in: fp32 x[4,2048,1024], Wq,Wk,Wv,Wp[1024,1024], bp[1024]; d_out: fp32 y.
// Pipeline: cvt(fp32->bf16 into ws) -> qkv -> attn -> proj.
// V stored TRANSPOSED [B,H,HD,T]. attn v9 = v8 + LDS double-buffer
// (stage t+1 issued before compute t; one barrier/tile drains prefetch after
// compute -> staging latency hidden) + s_setprio(1) around compute phase.

#define B_  4
#define T_  2048
#define D_  1024
#define H_  16
#define HD_ 64
#define M_  (B_ * T_)   // 8192 rows

typedef short bf16x8 __attribute__((ext_vector_type(8)));
typedef float f32x4  __attribute__((ext_vector_type(4)));

__device__ __forceinline__ f32x4 mfma16(bf16x8 a, bf16x8 b, f32x4 c) {
    return __builtin_amdgcn_mfma_f32_16x16x32_bf16(a, b, c, 0, 0, 0);
}

__device__ __forceinline__ void gl_lds16(const unsigned short* g, unsigned short* l) {
    __builtin_amdgcn_global_load_lds(
        (const __attribute__((address_space(1))) void*)g,
        (__attribute__((address_space(3))) void*)l, 16, 0, 0);
}

__device__ __forceinline__ unsigned short f2bf(float f) {
    union { __hip_bfloat16 h; unsigned short u; } cv;
    cv.h = __float2bfloat16(f);
    return cv.u;
}
__device__ __forceinline__ float bf2f(unsigned short u) {
    return __uint_as_float(((unsigned)u) << 16);
}
__device__ __forceinline__ float exp2_fast(float x) {
    return __builtin_amdgcn_exp2f(x);   // v_exp_f32: 2^x
}

struct su4 { unsigned short x, y, z, w; };

// ---------------------------------------------------------------------------
__global__ __launch_bounds__(256)
void cvt_kernel(const float* __restrict__ in, unsigned short* __restrict__ out) {
    const int i = blockIdx.x * 256 + threadIdx.x;
    const float4 v = ((const float4*)in)[i];
    su4 o;
    o.x = f2bf(v.x); o.y = f2bf(v.y); o.z = f2bf(v.z); o.w = f2bf(v.w);
    ((su4*)out)[i] = o;
}

__global__ __launch_bounds__(256)
void cvtw_kernel(const float* __restrict__ w0, const float* __restrict__ w1,
                 const float* __restrict__ w2, const float* __restrict__ w3,
                 unsigned short* __restrict__ o0, unsigned short* __restrict__ o1,
                 unsigned short* __restrict__ o2, unsigned short* __restrict__ o3) {
    const int y = blockIdx.y;
    const float* in       = (y == 0) ? w0 : (y == 1) ? w1 : (y == 2) ? w2 : w3;
    unsigned short* out   = (y == 0) ? o0 : (y == 1) ? o1 : (y == 2) ? o2 : o3;
    const int i = blockIdx.x * 256 + threadIdx.x;
    const float4 v = ((const float4*)in)[i];
    su4 o;
    o.x = f2bf(v.x); o.y = f2bf(v.y); o.z = f2bf(v.z); o.w = f2bf(v.w);
    ((su4*)out)[i] = o;
}

// ---------------------------------------------------------------------------
// Fused QKV GEMM: C = X @ W^T.  Q,K scattered to [B,H,T,HD]; V to [B,H,HD,T]
// via operand-swapped MFMA (acc holds C^T for the V section).
// ---------------------------------------------------------------------------
__global__ __launch_bounds__(256, 2)
void qkv_kernel(const unsigned short* __restrict__ X,
                const unsigned short* __restrict__ Wq,
                const unsigned short* __restrict__ Wk,
                const unsigned short* __restrict__ Wv,
                unsigned short* __restrict__ Qo,
                unsigned short* __restrict__ Ko,
                unsigned short* __restrict__ Vo)
{
    __shared__ unsigned short As[128 * 64];
    __shared__ unsigned short Bs[128 * 64];

    const int m0 = blockIdx.x * 128;
    const int by = blockIdx.y;
    const unsigned short* W = (by < 8) ? Wq : (by < 16) ? Wk : Wv;
    unsigned short*       O = (by < 8) ? Qo : (by < 16) ? Ko : Vo;
    const int n0   = (by & 7) * 128;
    const bool vsec = (by >= 16);
    const int tid  = threadIdx.x;
    const int lane = tid & 63;
    const int wv   = tid >> 6;
    const int wr   = (wv >> 1) * 64;
    const int wc   = (wv & 1) * 64;
    const int g    = lane >> 4;
    const int c    = lane & 15;

    f32x4 acc[4][4] = {};

    for (int k0 = 0; k0 < D_; k0 += 64) {
        #pragma unroll
        for (int i = 0; i < 4; ++i) {
            const int flat = i * 2048 + tid * 8;
            const int row = flat >> 6, col = flat & 63;
            gl_lds16(X + (size_t)(m0 + row) * D_ + k0 + col, As + flat);
            gl_lds16(W + (size_t)(n0 + row) * D_ + k0 + col, Bs + flat);
        }
        __syncthreads();
        #pragma unroll
        for (int kk = 0; kk < 64; kk += 32) {
            bf16x8 af[4], bg[4];
            #pragma unroll
            for (int mi = 0; mi < 4; ++mi)
                af[mi] = *(const bf16x8*)(As + (wr + mi * 16 + c) * 64 + kk + g * 8);
            #pragma unroll
            for (int ni = 0; ni < 4; ++ni)
                bg[ni] = *(const bf16x8*)(Bs + (wc + ni * 16 + c) * 64 + kk + g * 8);
            if (!vsec) {
                #pragma unroll
                for (int mi = 0; mi < 4; ++mi)
                    #pragma unroll
                    for (int ni = 0; ni < 4; ++ni)
                        acc[mi][ni] = mfma16(af[mi], bg[ni], acc[mi][ni]);
            } else {
                #pragma unroll
                for (int mi = 0; mi < 4; ++mi)
                    #pragma unroll
                    for (int ni = 0; ni < 4; ++ni)
                        acc[mi][ni] = mfma16(bg[ni], af[mi], acc[mi][ni]);
            }
        }
        __syncthreads();
    }

    if (!vsec) {
        #pragma unroll
        for (int mi = 0; mi < 4; ++mi)
            #pragma unroll
            for (int ni = 0; ni < 4; ++ni)
                #pragma unroll
                for (int r = 0; r < 4; ++r) {
                    const int m = m0 + wr + mi * 16 + g * 4 + r;
                    const int n = n0 + wc + ni * 16 + c;
                    const int b = m >> 11, t = m & (T_ - 1);
                    const int h = n >> 6,  hd = n & 63;
                    O[((size_t)((b << 4) + h) * T_ + t) * HD_ + hd] = f2bf(acc[mi][ni][r]);
                }
    } else {
        #pragma unroll
        for (int mi = 0; mi < 4; ++mi)
            #pragma unroll
            for (int ni = 0; ni < 4; ++ni)
                #pragma unroll
                for (int r = 0; r < 4; ++r) {
                    const int n = n0 + wc + ni * 16 + g * 4 + r;
                    const int m = m0 + wr + mi * 16 + c;
                    const int b = m >> 11, t = m & (T_ - 1);
                    const int h = n >> 6,  hd = n & 63;
                    O[((size_t)((b << 4) + h) * HD_ + hd) * T_ + t] = f2bf(acc[mi][ni][r]);
                }
    }
}

// ---------------------------------------------------------------------------
// P-transpose helper (verified lane math).
// ---------------------------------------------------------------------------
__device__ __forceinline__ bf16x8 ptrans(const f32x4& p0, const f32x4& p1,
                                         int lane, int g, int c) {
    unsigned int P32[2][2];
    P32[0][0] = (unsigned int)f2bf(p0[0]) | ((unsigned int)f2bf(p0[1]) << 16);
    P32[0][1] = (unsigned int)f2bf(p0[2]) | ((unsigned int)f2bf(p0[3]) << 16);
    P32[1][0] = (unsigned int)f2bf(p1[0]) | ((unsigned int)f2bf(p1[1]) << 16);
    P32[1][1] = (unsigned int)f2bf(p1[2]) | ((unsigned int)f2bf(p1[3]) << 16);
    const int sl0 = c + ((lane & 16) << 1);
    const int sl1 = sl0 + 16;
    const int q00 = __shfl((int)P32[0][0], sl0), q10 = __shfl((int)P32[1][0], sl0);
    const int q01 = __shfl((int)P32[0][1], sl0), q11 = __shfl((int)P32[1][1], sl0);
    const int q02 = __shfl((int)P32[0][0], sl1), q12 = __shfl((int)P32[1][0], sl1);
    const int q03 = __shfl((int)P32[0][1], sl1), q13 = __shfl((int)P32[1][1], sl1);
    const bool nhi = (g & 2) != 0;
    union { unsigned int u[4]; bf16x8 v; } pf;
    pf.u[0] = nhi ? q10 : q00;
    pf.u[1] = nhi ? q11 : q01;
    pf.u[2] = nhi ? q12 : q02;
    pf.u[3] = nhi ? q13 : q03;
    return pf.v;
}

// ---------------------------------------------------------------------------
// Causal flash attention v9: double-buffered LDS staging (prefetch t+1 before
// computing t; one barrier/tile), setprio around compute, defer-max, LPT grid.
// LDS: 2 x (K[64][64] + V^T[64][64]) bf16 = 32KB -> 5 blocks/CU.
// Swizzle: phys_byte = row*128 + (log_byte ^ ((row&3)<<5)); staged via
// linear gl_lds dest + pre-swizzled global source (involution).
// ---------------------------------------------------------------------------
__global__ __launch_bounds__(256, 4)
void attn_kernel(const unsigned short* __restrict__ Q,
                 const unsigned short* __restrict__ K,
                 const unsigned short* __restrict__ VT,
                 unsigned short* __restrict__ Y)
{
    __shared__ unsigned short Ks[2][4096];   // K tiles, swizzled
    __shared__ unsigned short Vs[2][4096];   // V^T tiles, swizzled

    const int bh = blockIdx.x;          // fast axis -> XCD panel residency
    const int qt = 31 - blockIdx.y;     // LPT: heaviest q-tiles first
    const unsigned short* Qp  = Q  + (size_t)bh * T_ * HD_;
    const unsigned short* Kp  = K  + (size_t)bh * T_ * HD_;
    const unsigned short* VTp = VT + (size_t)bh * HD_ * T_;
    const int b = bh >> 4, h = bh & 15;

    const int tid  = threadIdx.x;
    const int lane = tid & 63;
    const int w    = tid >> 6;
    const int g    = lane >> 4;
    const int c    = lane & 15;
    const float SC = 0.18033688011112042f;   // (1/sqrt(64)) * log2(e)

    const int qw = qt * 64 + w * 16;
    const int nt = qt + 1;              // 64-key tiles; last is diagonal

    // Staging constants (two 16B segments per 8KB half-tile)
    int srow[2], scol[2];
    #pragma unroll
    for (int i = 0; i < 2; ++i) {
        const int L = (i * 256 + tid) * 16;
        srow[i] = L >> 7;                                   // 0..63
        scol[i] = (L & 127) ^ ((srow[i] & 3) << 5);         // pre-swizzled src col (bytes)
    }

    // Q as B-operand frags, pre-scaled (log2 domain)
    bf16x8 qf[2];
    #pragma unroll
    for (int dk = 0; dk < 2; ++dk) {
        bf16x8 t = *(const bf16x8*)(Qp + (size_t)(qw + c) * HD_ + dk * 32 + g * 8);
        #pragma unroll
        for (int j = 0; j < 8; ++j)
            t[j] = (short)f2bf(bf2f((unsigned short)t[j]) * SC);
        qf[dk] = t;
    }

    float m_l = -1e30f, l_l = 0.f;
    f32x4 oacc[4] = {};
    const int swz = (c & 3) << 5;       // per-lane read swizzle (bytes)

    // stage one 64-key tile into buffer `buf`
    auto stage = [&](int buf, int tb) {
        #pragma unroll
        for (int i = 0; i < 2; ++i) {
            const int L = (i * 256 + tid) * 16;
            gl_lds16(Kp + (size_t)(tb + srow[i]) * HD_ + (scol[i] >> 1),
                     &Ks[buf][L >> 1]);
            gl_lds16(VTp + (size_t)srow[i] * T_ + tb + (scol[i] >> 1),
                     &Vs[buf][L >> 1]);
        }
    };

    stage(0, 0);
    __syncthreads();
    int cur = 0;

    for (int ti = 0; ti < nt; ++ti) {
        const int tb = ti << 6;
        const bool last = (ti == nt - 1);

        // ---- prefetch next tile into alternate buffer (latency hides
        //      under this tile's compute; drained by the end barrier)
        if (!last) stage(cur ^ 1, tb + 64);

        __builtin_amdgcn_s_setprio(1);

        // ---- QK^T (swapped): sA (keys tb..tb+31), sB (tb+32..tb+63)
        const char* Kb = (const char*)Ks[cur];
        const char* Vb = (const char*)Vs[cur];
        f32x4 sA[2] = {}, sB[2] = {};
        #pragma unroll
        for (int ni = 0; ni < 2; ++ni)
            #pragma unroll
            for (int dk = 0; dk < 2; ++dk) {
                const int col = (dk * 64 + g * 16) ^ swz;
                const bf16x8 kA = *(const bf16x8*)(Kb + (ni * 16 + c) * 128 + col);
                const bf16x8 kB = *(const bf16x8*)(Kb + (32 + ni * 16 + c) * 128 + col);
                sA[ni] = mfma16(kA, qf[dk], sA[ni]);
                sB[ni] = mfma16(kB, qf[dk], sB[ni]);
            }

        // ---- mask (diagonal tile only)
        if (last) {
            #pragma unroll
            for (int ni = 0; ni < 2; ++ni)
                #pragma unroll
                for (int r = 0; r < 4; ++r) {
                    const int kA = tb + ni * 16 + g * 4 + r;
                    sA[ni][r] = (kA      <= qw + c) ? sA[ni][r] : -1e30f;
                    sB[ni][r] = (kA + 32 <= qw + c) ? sB[ni][r] : -1e30f;
                }
        }

        // ---- online softmax (per-lane over 16 vals + 2 shuffles) + defer-max
        float pmax = sA[0][0];
        #pragma unroll
        for (int ni = 0; ni < 2; ++ni)
            #pragma unroll
            for (int r = 0; r < 4; ++r) {
                pmax = fmaxf(pmax, sA[ni][r]);
                pmax = fmaxf(pmax, sB[ni][r]);
            }
        pmax = fmaxf(pmax, __shfl_xor(pmax, 16));
        pmax = fmaxf(pmax, __shfl_xor(pmax, 32));

        const bool skip = __all(pmax - m_l <= 8.0f);
        float al = 1.f;
        if (!skip) {
            const float mn = fmaxf(m_l, pmax);
            al = exp2_fast(m_l - mn);
            m_l = mn;
        }

        float rs = 0.f;
        #pragma unroll
        for (int ni = 0; ni < 2; ++ni)
            #pragma unroll
            for (int r = 0; r < 4; ++r) {
                const float eA = exp2_fast(sA[ni][r] - m_l);
                const float eB = exp2_fast(sB[ni][r] - m_l);
                sA[ni][r] = eA; sB[ni][r] = eB;
                rs += eA + eB;
            }
        rs += __shfl_xor(rs, 16);
        rs += __shfl_xor(rs, 32);
        l_l = l_l * al + rs;

        // ---- P transpose to PV A-fragments
        const bf16x8 pfA = ptrans(sA[0], sA[1], lane, g, c);
        const bf16x8 pfB = ptrans(sB[0], sB[1], lane, g, c);

        // ---- rescale (skipped when deferred) + PV (swapped)
        #pragma unroll
        for (int dn = 0; dn < 4; ++dn) {
            const int row = dn * 16 + c;
            const bf16x8 vA = *(const bf16x8*)(Vb + row * 128 + ((g * 16)      ^ swz));
            const bf16x8 vB = *(const bf16x8*)(Vb + row * 128 + ((64 + g * 16) ^ swz));
            if (!skip) {
                #pragma unroll
                for (int r = 0; r < 4; ++r)
                    oacc[dn][r] *= al;
            }
            oacc[dn] = mfma16(vA, pfA, oacc[dn]);
            oacc[dn] = mfma16(vB, pfB, oacc[dn]);
        }

        __builtin_amdgcn_s_setprio(0);
        __syncthreads();               // drains prefetch; protects cur buffer
        cur ^= 1;
    }

    // ---- epilogue: O[q = qw+c][d = dn*16 + g*4 + r]
    const float li = 1.f / l_l;
    const size_t rowoff = (size_t)(b * T_ + qw + c) * D_ + h * 64;
    #pragma unroll
    for (int dn = 0; dn < 4; ++dn) {
        const unsigned int u0 = (unsigned int)f2bf(oacc[dn][0] * li)
                              | ((unsigned int)f2bf(oacc[dn][1] * li) << 16);
        const unsigned int u1 = (unsigned int)f2bf(oacc[dn][2] * li)
                              | ((unsigned int)f2bf(oacc[dn][3] * li) << 16);
        uint2 st; st.x = u0; st.y = u1;
        *(uint2*)(Y + rowoff + dn * 16 + g * 4) = st;
    }
}

// ---------------------------------------------------------------------------
// Output projection:  out = Y @ Wp^T + bp.  Y bf16[8192,1024]; out fp32.
// ---------------------------------------------------------------------------
__global__ __launch_bounds__(256, 2)
void proj_kernel(const unsigned short* __restrict__ Yin,
                 const unsigned short* __restrict__ Wp,
                 const float* __restrict__ bp,
                 float* __restrict__ Out)
{
    __shared__ unsigned short As[128 * 64];
    __shared__ unsigned short Bs[128 * 64];

    const int m0 = blockIdx.x * 128;
    const int n0 = blockIdx.y * 128;
    const int tid  = threadIdx.x;
    const int lane = tid & 63;
    const int wv   = tid >> 6;
    const int wr   = (wv >> 1) * 64;
    const int wc   = (wv & 1) * 64;
    const int g    = lane >> 4;
    const int c    = lane & 15;

    f32x4 acc[4][4] = {};

    for (int k0 = 0; k0 < D_; k0 += 64) {
        #pragma unroll
        for (int i = 0; i < 4; ++i) {
            const int flat = i * 2048 + tid * 8;
            const int row = flat >> 6, col = flat & 63;
            gl_lds16(Yin + (size_t)(m0 + row) * D_ + k0 + col, As + flat);
            gl_lds16(Wp  + (size_t)(n0 + row) * D_ + k0 + col, Bs + flat);
        }
        __syncthreads();
        #pragma unroll
        for (int kk = 0; kk < 64; kk += 32) {
            bf16x8 af[4], bg[4];
            #pragma unroll
            for (int mi = 0; mi < 4; ++mi)
                af[mi] = *(const bf16x8*)(As + (wr + mi * 16 + c) * 64 + kk + g * 8);
            #pragma unroll
            for (int ni = 0; ni < 4; ++ni)
                bg[ni] = *(const bf16x8*)(Bs + (wc + ni * 16 + c) * 64 + kk + g * 8);
            #pragma unroll
            for (int mi = 0; mi < 4; ++mi)
                #pragma unroll
                for (int ni = 0; ni < 4; ++ni)
                    acc[mi][ni] = mfma16(af[mi], bg[ni], acc[mi][ni]);
        }
        __syncthreads();
    }

    #pragma unroll
    for (int mi = 0; mi < 4; ++mi) {
        #pragma unroll
        for (int ni = 0; ni < 4; ++ni) {
            const int n = n0 + wc + ni * 16 + c;
            const float bb = bp[n];
            #pragma unroll
            for (int r = 0; r < 4; ++r) {
                const int m = m0 + wr + mi * 16 + g * 4 + r;
                Out[(size_t)m * D_ + n] = acc[mi][ni][r] + bb;
            }
        }
    }
}

// ---------------------------------------------------------------------------
extern "C" void kernel_launch(void* const* d_in, const int* in_sizes, int n_in,
                              void* d_out, int out_size, void* d_ws, size_t ws_size,
                              hipStream_t stream) {
    const float* x  = (const float*)d_in[0];
    const float* Wq = (const float*)d_in[1];
    const float* Wk = (const float*)d_in[2];
    const float* Wv = (const float*)d_in[3];
    const float* Wp = (const float*)d_in[4];
    const float* bp = (const float*)d_in[5];
    float* out = (float*)d_out;

    const size_t SZ  = (size_t)M_ * D_;      // 8388608
    const size_t WSZ = (size_t)D_ * D_;      // 1048576
    unsigned short* ws = (unsigned short*)d_ws;
    unsigned short* XB  = ws;                 // also Y after qkv
    unsigned short* WQB = XB  + SZ;
    unsigned short* WKB = WQB + WSZ;
    unsigned short* WVB = WKB + WSZ;
    unsigned short* WPB = WVB + WSZ;
    unsigned short* Qw  = WPB + WSZ;
    unsigned short* Kw  = Qw + SZ;
    unsigned short* Vw  = Kw + SZ;            // V^T [B,H,HD,T]
    unsigned short* Yw  = XB;                 // overlay: x_bf16 dead after qkv

    dim3 blk(256);
    cvt_kernel <<<dim3(SZ / 1024),     blk, 0, stream>>>(x, XB);
    cvtw_kernel<<<dim3(WSZ / 1024, 4), blk, 0, stream>>>(Wq, Wk, Wv, Wp, WQB, WKB, WVB, WPB);

    qkv_kernel <<<dim3(M_ / 128, 24), blk, 0, stream>>>(XB, WQB, WKB, WVB, Qw, Kw, Vw);
    attn_kernel<<<dim3(B_ * H_, T_ / 64), blk, 0, stream>>>(Qw, Kw, Vw, Yw);
    proj_kernel<<<dim3(M_ / 128, D_ / 128), blk, 0, stream>>>(Yw, WPB, bp, out);
}

// Round 12
// 195.996 us; speedup vs baseline: 1.1635x; 1.0341x over previous
//
#include <hip/hip_runtime.h>
#include <hip/hip_bf16.h>
#include <math.h>

// Problem: CausalSelfAttention  B=4 T=2048 D=1024 H=16 HD=64
// d_in: fp32 x[4,2048,1024], Wq,Wk,Wv,Wp[1024,1024], bp[1024]; d_out: fp32 y.
// Pipeline: cvt(fp32->bf16 into ws) -> qkv -> attn -> proj.
// V stored TRANSPOSED [B,H,HD,T]. attn v10 = v9 with the m214-verified
// 3-bit LDS swizzle (byte ^= (row&7)<<4, both-sides involution) replacing
// the 2-bit variant, and a 2x-unrolled tile loop with compile-time buffer
// selection (hoistable LDS read addresses).

#define B_  4
#define T_  2048
#define D_  1024
#define H_  16
#define HD_ 64
#define M_  (B_ * T_)   // 8192 rows

typedef short bf16x8 __attribute__((ext_vector_type(8)));
typedef float f32x4  __attribute__((ext_vector_type(4)));

__device__ __forceinline__ f32x4 mfma16(bf16x8 a, bf16x8 b, f32x4 c) {
    return __builtin_amdgcn_mfma_f32_16x16x32_bf16(a, b, c, 0, 0, 0);
}

__device__ __forceinline__ void gl_lds16(const unsigned short* g, unsigned short* l) {
    __builtin_amdgcn_global_load_lds(
        (const __attribute__((address_space(1))) void*)g,
        (__attribute__((address_space(3))) void*)l, 16, 0, 0);
}

__device__ __forceinline__ unsigned short f2bf(float f) {
    union { __hip_bfloat16 h; unsigned short u; } cv;
    cv.h = __float2bfloat16(f);
    return cv.u;
}
__device__ __forceinline__ float bf2f(unsigned short u) {
    return __uint_as_float(((unsigned)u) << 16);
}
__device__ __forceinline__ float exp2_fast(float x) {
    return __builtin_amdgcn_exp2f(x);   // v_exp_f32: 2^x
}

struct su4 { unsigned short x, y, z, w; };

// ---------------------------------------------------------------------------
__global__ __launch_bounds__(256)
void cvt_kernel(const float* __restrict__ in, unsigned short* __restrict__ out) {
    const int i = blockIdx.x * 256 + threadIdx.x;
    const float4 v = ((const float4*)in)[i];
    su4 o;
    o.x = f2bf(v.x); o.y = f2bf(v.y); o.z = f2bf(v.z); o.w = f2bf(v.w);
    ((su4*)out)[i] = o;
}

__global__ __launch_bounds__(256)
void cvtw_kernel(const float* __restrict__ w0, const float* __restrict__ w1,
                 const float* __restrict__ w2, const float* __restrict__ w3,
                 unsigned short* __restrict__ o0, unsigned short* __restrict__ o1,
                 unsigned short* __restrict__ o2, unsigned short* __restrict__ o3) {
    const int y = blockIdx.y;
    const float* in       = (y == 0) ? w0 : (y == 1) ? w1 : (y == 2) ? w2 : w3;
    unsigned short* out   = (y == 0) ? o0 : (y == 1) ? o1 : (y == 2) ? o2 : o3;
    const int i = blockIdx.x * 256 + threadIdx.x;
    const float4 v = ((const float4*)in)[i];
    su4 o;
    o.x = f2bf(v.x); o.y = f2bf(v.y); o.z = f2bf(v.z); o.w = f2bf(v.w);
    ((su4*)out)[i] = o;
}

// ---------------------------------------------------------------------------
// Fused QKV GEMM: C = X @ W^T.  Q,K scattered to [B,H,T,HD]; V to [B,H,HD,T]
// via operand-swapped MFMA (acc holds C^T for the V section).
// ---------------------------------------------------------------------------
__global__ __launch_bounds__(256, 2)
void qkv_kernel(const unsigned short* __restrict__ X,
                const unsigned short* __restrict__ Wq,
                const unsigned short* __restrict__ Wk,
                const unsigned short* __restrict__ Wv,
                unsigned short* __restrict__ Qo,
                unsigned short* __restrict__ Ko,
                unsigned short* __restrict__ Vo)
{
    __shared__ unsigned short As[128 * 64];
    __shared__ unsigned short Bs[128 * 64];

    const int m0 = blockIdx.x * 128;
    const int by = blockIdx.y;
    const unsigned short* W = (by < 8) ? Wq : (by < 16) ? Wk : Wv;
    unsigned short*       O = (by < 8) ? Qo : (by < 16) ? Ko : Vo;
    const int n0   = (by & 7) * 128;
    const bool vsec = (by >= 16);
    const int tid  = threadIdx.x;
    const int lane = tid & 63;
    const int wv   = tid >> 6;
    const int wr   = (wv >> 1) * 64;
    const int wc   = (wv & 1) * 64;
    const int g    = lane >> 4;
    const int c    = lane & 15;

    f32x4 acc[4][4] = {};

    for (int k0 = 0; k0 < D_; k0 += 64) {
        #pragma unroll
        for (int i = 0; i < 4; ++i) {
            const int flat = i * 2048 + tid * 8;
            const int row = flat >> 6, col = flat & 63;
            gl_lds16(X + (size_t)(m0 + row) * D_ + k0 + col, As + flat);
            gl_lds16(W + (size_t)(n0 + row) * D_ + k0 + col, Bs + flat);
        }
        __syncthreads();
        #pragma unroll
        for (int kk = 0; kk < 64; kk += 32) {
            bf16x8 af[4], bg[4];
            #pragma unroll
            for (int mi = 0; mi < 4; ++mi)
                af[mi] = *(const bf16x8*)(As + (wr + mi * 16 + c) * 64 + kk + g * 8);
            #pragma unroll
            for (int ni = 0; ni < 4; ++ni)
                bg[ni] = *(const bf16x8*)(Bs + (wc + ni * 16 + c) * 64 + kk + g * 8);
            if (!vsec) {
                #pragma unroll
                for (int mi = 0; mi < 4; ++mi)
                    #pragma unroll
                    for (int ni = 0; ni < 4; ++ni)
                        acc[mi][ni] = mfma16(af[mi], bg[ni], acc[mi][ni]);
            } else {
                #pragma unroll
                for (int mi = 0; mi < 4; ++mi)
                    #pragma unroll
                    for (int ni = 0; ni < 4; ++ni)
                        acc[mi][ni] = mfma16(bg[ni], af[mi], acc[mi][ni]);
            }
        }
        __syncthreads();
    }

    if (!vsec) {
        #pragma unroll
        for (int mi = 0; mi < 4; ++mi)
            #pragma unroll
            for (int ni = 0; ni < 4; ++ni)
                #pragma unroll
                for (int r = 0; r < 4; ++r) {
                    const int m = m0 + wr + mi * 16 + g * 4 + r;
                    const int n = n0 + wc + ni * 16 + c;
                    const int b = m >> 11, t = m & (T_ - 1);
                    const int h = n >> 6,  hd = n & 63;
                    O[((size_t)((b << 4) + h) * T_ + t) * HD_ + hd] = f2bf(acc[mi][ni][r]);
                }
    } else {
        #pragma unroll
        for (int mi = 0; mi < 4; ++mi)
            #pragma unroll
            for (int ni = 0; ni < 4; ++ni)
                #pragma unroll
                for (int r = 0; r < 4; ++r) {
                    const int n = n0 + wc + ni * 16 + g * 4 + r;
                    const int m = m0 + wr + mi * 16 + c;
                    const int b = m >> 11, t = m & (T_ - 1);
                    const int h = n >> 6,  hd = n & 63;
                    O[((size_t)((b << 4) + h) * HD_ + hd) * T_ + t] = f2bf(acc[mi][ni][r]);
                }
    }
}

// ---------------------------------------------------------------------------
// P-transpose helper (verified lane math).
// ---------------------------------------------------------------------------
__device__ __forceinline__ bf16x8 ptrans(const f32x4& p0, const f32x4& p1,
                                         int lane, int g, int c) {
    unsigned int P32[2][2];
    P32[0][0] = (unsigned int)f2bf(p0[0]) | ((unsigned int)f2bf(p0[1]) << 16);
    P32[0][1] = (unsigned int)f2bf(p0[2]) | ((unsigned int)f2bf(p0[3]) << 16);
    P32[1][0] = (unsigned int)f2bf(p1[0]) | ((unsigned int)f2bf(p1[1]) << 16);
    P32[1][1] = (unsigned int)f2bf(p1[2]) | ((unsigned int)f2bf(p1[3]) << 16);
    const int sl0 = c + ((lane & 16) << 1);
    const int sl1 = sl0 + 16;
    const int q00 = __shfl((int)P32[0][0], sl0), q10 = __shfl((int)P32[1][0], sl0);
    const int q01 = __shfl((int)P32[0][1], sl0), q11 = __shfl((int)P32[1][1], sl0);
    const int q02 = __shfl((int)P32[0][0], sl1), q12 = __shfl((int)P32[1][0], sl1);
    const int q03 = __shfl((int)P32[0][1], sl1), q13 = __shfl((int)P32[1][1], sl1);
    const bool nhi = (g & 2) != 0;
    union { unsigned int u[4]; bf16x8 v; } pf;
    pf.u[0] = nhi ? q10 : q00;
    pf.u[1] = nhi ? q11 : q01;
    pf.u[2] = nhi ? q12 : q02;
    pf.u[3] = nhi ? q13 : q03;
    return pf.v;
}

// ---------------------------------------------------------------------------
// Causal flash attention v10: double-buffered LDS staging, 2x-unrolled loop
// (compile-time buffer selection), 3-bit XOR swizzle (m214 recipe), setprio,
// defer-max, LPT grid.
// LDS: 2 x (K[64][64] + V^T[64][64]) bf16 = 32KB.
// Swizzle: phys_byte = row*128 + (log_byte ^ ((row&7)<<4)); staged via
// linear gl_lds dest + pre-swizzled global source (involution).
// ---------------------------------------------------------------------------
__global__ __launch_bounds__(256, 4)
void attn_kernel(const unsigned short* __restrict__ Q,
                 const unsigned short* __restrict__ K,
                 const unsigned short* __restrict__ VT,
                 unsigned short* __restrict__ Y)
{
    __shared__ unsigned short Ks[2][4096];   // K tiles, swizzled
    __shared__ unsigned short Vs[2][4096];   // V^T tiles, swizzled

    const int bh = blockIdx.x;          // fast axis -> XCD panel residency
    const int qt = 31 - blockIdx.y;     // LPT: heaviest q-tiles first
    const unsigned short* Qp  = Q  + (size_t)bh * T_ * HD_;
    const unsigned short* Kp  = K  + (size_t)bh * T_ * HD_;
    const unsigned short* VTp = VT + (size_t)bh * HD_ * T_;
    const int b = bh >> 4, h = bh & 15;

    const int tid  = threadIdx.x;
    const int lane = tid & 63;
    const int w    = tid >> 6;
    const int g    = lane >> 4;
    const int c    = lane & 15;
    const float SC = 0.18033688011112042f;   // (1/sqrt(64)) * log2(e)

    const int qw = qt * 64 + w * 16;
    const int nt = qt + 1;              // 64-key tiles; last is diagonal

    // Staging constants (two 16B segments per 8KB half-tile); 3-bit swizzle
    int srow[2], scol[2];
    #pragma unroll
    for (int i = 0; i < 2; ++i) {
        const int L = (i * 256 + tid) * 16;
        srow[i] = L >> 7;                                   // 0..63
        scol[i] = (L & 127) ^ ((srow[i] & 7) << 4);         // pre-swizzled src col (bytes)
    }

    // Q as B-operand frags, pre-scaled (log2 domain)
    bf16x8 qf[2];
    #pragma unroll
    for (int dk = 0; dk < 2; ++dk) {
        bf16x8 t = *(const bf16x8*)(Qp + (size_t)(qw + c) * HD_ + dk * 32 + g * 8);
        #pragma unroll
        for (int j = 0; j < 8; ++j)
            t[j] = (short)f2bf(bf2f((unsigned short)t[j]) * SC);
        qf[dk] = t;
    }

    float m_l = -1e30f, l_l = 0.f;
    f32x4 oacc[4] = {};
    const int swz = (c & 7) << 4;       // per-lane read swizzle (bytes); read rows all have row&7 == c&7

    // stage one 64-key tile into buffer `buf`
    auto stage = [&](int buf, int tb) {
        #pragma unroll
        for (int i = 0; i < 2; ++i) {
            const int L = (i * 256 + tid) * 16;
            gl_lds16(Kp + (size_t)(tb + srow[i]) * HD_ + (scol[i] >> 1),
                     &Ks[buf][L >> 1]);
            gl_lds16(VTp + (size_t)srow[i] * T_ + tb + (scol[i] >> 1),
                     &Vs[buf][L >> 1]);
        }
    };

    // compute one 64-key tile from the given buffers
    auto compute = [&](const unsigned short* Kbuf, const unsigned short* Vbuf,
                       int tb, bool last) {
        const char* Kb = (const char*)Kbuf;
        const char* Vb = (const char*)Vbuf;

        __builtin_amdgcn_s_setprio(1);

        // ---- QK^T (swapped): sA (keys tb..tb+31), sB (tb+32..tb+63)
        f32x4 sA[2] = {}, sB[2] = {};
        #pragma unroll
        for (int ni = 0; ni < 2; ++ni)
            #pragma unroll
            for (int dk = 0; dk < 2; ++dk) {
                const int col = (dk * 64 + g * 16) ^ swz;
                const bf16x8 kA = *(const bf16x8*)(Kb + (ni * 16 + c) * 128 + col);
                const bf16x8 kB = *(const bf16x8*)(Kb + (32 + ni * 16 + c) * 128 + col);
                sA[ni] = mfma16(kA, qf[dk], sA[ni]);
                sB[ni] = mfma16(kB, qf[dk], sB[ni]);
            }

        // ---- mask (diagonal tile only)
        if (last) {
            #pragma unroll
            for (int ni = 0; ni < 2; ++ni)
                #pragma unroll
                for (int r = 0; r < 4; ++r) {
                    const int kA = tb + ni * 16 + g * 4 + r;
                    sA[ni][r] = (kA      <= qw + c) ? sA[ni][r] : -1e30f;
                    sB[ni][r] = (kA + 32 <= qw + c) ? sB[ni][r] : -1e30f;
                }
        }

        // ---- online softmax (per-lane over 16 vals + 2 shuffles) + defer-max
        float pmax = sA[0][0];
        #pragma unroll
        for (int ni = 0; ni < 2; ++ni)
            #pragma unroll
            for (int r = 0; r < 4; ++r) {
                pmax = fmaxf(pmax, sA[ni][r]);
                pmax = fmaxf(pmax, sB[ni][r]);
            }
        pmax = fmaxf(pmax, __shfl_xor(pmax, 16));
        pmax = fmaxf(pmax, __shfl_xor(pmax, 32));

        const bool skip = __all(pmax - m_l <= 8.0f);
        float al = 1.f;
        if (!skip) {
            const float mn = fmaxf(m_l, pmax);
            al = exp2_fast(m_l - mn);
            m_l = mn;
        }

        float rs = 0.f;
        #pragma unroll
        for (int ni = 0; ni < 2; ++ni)
            #pragma unroll
            for (int r = 0; r < 4; ++r) {
                const float eA = exp2_fast(sA[ni][r] - m_l);
                const float eB = exp2_fast(sB[ni][r] - m_l);
                sA[ni][r] = eA; sB[ni][r] = eB;
                rs += eA + eB;
            }
        rs += __shfl_xor(rs, 16);
        rs += __shfl_xor(rs, 32);
        l_l = l_l * al + rs;

        // ---- P transpose to PV A-fragments
        const bf16x8 pfA = ptrans(sA[0], sA[1], lane, g, c);
        const bf16x8 pfB = ptrans(sB[0], sB[1], lane, g, c);

        // ---- rescale (skipped when deferred) + PV (swapped)
        #pragma unroll
        for (int dn = 0; dn < 4; ++dn) {
            const int row = dn * 16 + c;
            const bf16x8 vA = *(const bf16x8*)(Vb + row * 128 + ((g * 16)      ^ swz));
            const bf16x8 vB = *(const bf16x8*)(Vb + row * 128 + ((64 + g * 16) ^ swz));
            if (!skip) {
                #pragma unroll
                for (int r = 0; r < 4; ++r)
                    oacc[dn][r] *= al;
            }
            oacc[dn] = mfma16(vA, pfA, oacc[dn]);
            oacc[dn] = mfma16(vB, pfB, oacc[dn]);
        }

        __builtin_amdgcn_s_setprio(0);
    };

    // 2x-unrolled double-buffer pipeline (compile-time buffer indices)
    stage(0, 0);
    __syncthreads();
    int ti = 0;
    for (;;) {
        if (ti + 1 < nt) stage(1, (ti + 1) << 6);
        compute(Ks[0], Vs[0], ti << 6, ti == nt - 1);
        __syncthreads();
        if (++ti >= nt) break;

        if (ti + 1 < nt) stage(0, (ti + 1) << 6);
        compute(Ks[1], Vs[1], ti << 6, ti == nt - 1);
        __syncthreads();
        if (++ti >= nt) break;
    }

    // ---- epilogue: O[q = qw+c][d = dn*16 + g*4 + r]
    const float li = 1.f / l_l;
    const size_t rowoff = (size_t)(b * T_ + qw + c) * D_ + h * 64;
    #pragma unroll
    for (int dn = 0; dn < 4; ++dn) {
        const unsigned int u0 = (unsigned int)f2bf(oacc[dn][0] * li)
                              | ((unsigned int)f2bf(oacc[dn][1] * li) << 16);
        const unsigned int u1 = (unsigned int)f2bf(oacc[dn][2] * li)
                              | ((unsigned int)f2bf(oacc[dn][3] * li) << 16);
        uint2 st; st.x = u0; st.y = u1;
        *(uint2*)(Y + rowoff + dn * 16 + g * 4) = st;
    }
}

// ---------------------------------------------------------------------------
// Output projection:  out = Y @ Wp^T + bp.  Y bf16[8192,1024]; out fp32.
// ---------------------------------------------------------------------------
__global__ __launch_bounds__(256, 2)
void proj_kernel(const unsigned short* __restrict__ Yin,
                 const unsigned short* __restrict__ Wp,
                 const float* __restrict__ bp,
                 float* __restrict__ Out)
{
    __shared__ unsigned short As[128 * 64];
    __shared__ unsigned short Bs[128 * 64];

    const int m0 = blockIdx.x * 128;
    const int n0 = blockIdx.y * 128;
    const int tid  = threadIdx.x;
    const int lane = tid & 63;
    const int wv   = tid >> 6;
    const int wr   = (wv >> 1) * 64;
    const int wc   = (wv & 1) * 64;
    const int g    = lane >> 4;
    const int c    = lane & 15;

    f32x4 acc[4][4] = {};

    for (int k0 = 0; k0 < D_; k0 += 64) {
        #pragma unroll
        for (int i = 0; i < 4; ++i) {
            const int flat = i * 2048 + tid * 8;
            const int row = flat >> 6, col = flat & 63;
            gl_lds16(Yin + (size_t)(m0 + row) * D_ + k0 + col, As + flat);
            gl_lds16(Wp  + (size_t)(n0 + row) * D_ + k0 + col, Bs + flat);
        }
        __syncthreads();
        #pragma unroll
        for (int kk = 0; kk < 64; kk += 32) {
            bf16x8 af[4], bg[4];
            #pragma unroll
            for (int mi = 0; mi < 4; ++mi)
                af[mi] = *(const bf16x8*)(As + (wr + mi * 16 + c) * 64 + kk + g * 8);
            #pragma unroll
            for (int ni = 0; ni < 4; ++ni)
                bg[ni] = *(const bf16x8*)(Bs + (wc + ni * 16 + c) * 64 + kk + g * 8);
            #pragma unroll
            for (int mi = 0; mi < 4; ++mi)
                #pragma unroll
                for (int ni = 0; ni < 4; ++ni)
                    acc[mi][ni] = mfma16(af[mi], bg[ni], acc[mi][ni]);
        }
        __syncthreads();
    }

    #pragma unroll
    for (int mi = 0; mi < 4; ++mi) {
        #pragma unroll
        for (int ni = 0; ni < 4; ++ni) {
            const int n = n0 + wc + ni * 16 + c;
            const float bb = bp[n];
            #pragma unroll
            for (int r = 0; r < 4; ++r) {
                const int m = m0 + wr + mi * 16 + g * 4 + r;
                Out[(size_t)m * D_ + n] = acc[mi][ni][r] + bb;
            }
        }
    }
}

// ---------------------------------------------------------------------------
extern "C" void kernel_launch(void* const* d_in, const int* in_sizes, int n_in,
                              void* d_out, int out_size, void* d_ws, size_t ws_size,
                              hipStream_t stream) {
    const float* x  = (const float*)d_in[0];
    const float* Wq = (const float*)d_in[1];
    const float* Wk = (const float*)d_in[2];
    const float* Wv = (const float*)d_in[3];
    const float* Wp = (const float*)d_in[4];
    const float* bp = (const float*)d_in[5];
    float* out = (float*)d_out;

    const size_t SZ  = (size_t)M_ * D_;      // 8388608
    const size_t WSZ = (size_t)D_ * D_;      // 1048576
    unsigned short* ws = (unsigned short*)d_ws;
    unsigned short* XB  = ws;                 // also Y after qkv
    unsigned short* WQB = XB  + SZ;
    unsigned short* WKB = WQB + WSZ;
    unsigned short* WVB = WKB + WSZ;
    unsigned short* WPB = WVB + WSZ;
    unsigned short* Qw  = WPB + WSZ;
    unsigned short* Kw  = Qw + SZ;
    unsigned short* Vw  = Kw + SZ;            // V^T [B,H,HD,T]
    unsigned short* Yw  = XB;                 // overlay: x_bf16 dead after qkv

    dim3 blk(256);
    cvt_kernel <<<dim3(SZ / 1024),     blk, 0, stream>>>(x, XB);
    cvtw_kernel<<<dim3(WSZ / 1024, 4), blk, 0, stream>>>(Wq, Wk, Wv, Wp, WQB, WKB, WVB, WPB);

    qkv_kernel <<<dim3(M_ / 128, 24), blk, 0, stream>>>(XB, WQB, WKB, WVB, Qw, Kw, Vw);
    attn_kernel<<<dim3(B_ * H_, T_ / 64), blk, 0, stream>>>(Qw, Kw, Vw, Yw);
    proj_kernel<<<dim3(M_ / 128, D_ / 128), blk, 0, stream>>>(Yw, WPB, bp, out);
}